// Round 1
// baseline (77.594 us; speedup 1.0000x reference)
//
#include <hip/hip_runtime.h>

#define BB 16
#define HH 480
#define WW 640
#define EPSF 1e-7f

// Per-batch fold: P = (K @ T)[:3,:]; M = P[:,:3] @ invK[:3,:3]; t = P[:,3]
// Output: Mt[b*12 + i*4 + j] = M[i][j] (j<3), Mt[b*12 + i*4 + 3] = t[i]
__global__ void cam2cam_precompute(const float* __restrict__ T,
                                   const float* __restrict__ K,
                                   const float* __restrict__ invK,
                                   float* __restrict__ Mt) {
    int b = threadIdx.x;
    if (b >= BB) return;
    const float* Kb  = K    + b * 16;
    const float* Tb  = T    + b * 16;
    const float* iKb = invK + b * 16;
    float P[3][4];
    #pragma unroll
    for (int i = 0; i < 3; ++i) {
        #pragma unroll
        for (int j = 0; j < 4; ++j) {
            float s = 0.f;
            #pragma unroll
            for (int k = 0; k < 4; ++k) s += Kb[i * 4 + k] * Tb[k * 4 + j];
            P[i][j] = s;
        }
    }
    float* o = Mt + b * 12;
    #pragma unroll
    for (int i = 0; i < 3; ++i) {
        #pragma unroll
        for (int j = 0; j < 3; ++j) {
            float s = 0.f;
            #pragma unroll
            for (int k = 0; k < 3; ++k) s += P[i][k] * iKb[k * 4 + j];
            o[i * 4 + j] = s;
        }
        o[i * 4 + 3] = P[i][3];
    }
}

__global__ __launch_bounds__(256) void cam2cam_warp(
    const float* __restrict__ img,
    const float* __restrict__ depth,
    const float* __restrict__ Mt,
    float* __restrict__ out) {
    const int HW = HH * WW;
    int idx = blockIdx.x * blockDim.x + threadIdx.x;
    if (idx >= BB * HW) return;
    int b = idx / HW;
    int p = idx - b * HW;
    int y = p / WW;
    int x = p - y * WW;

    const float* m = Mt + b * 12;
    float d = depth[idx];  // depth is (B,1,H,W): flat index matches

    float fxp = (float)x, fyp = (float)y;
    // cam ray = M @ [x,y,1]; cp = d*ray + t
    float rx = m[0] * fxp + m[1] * fyp + m[2];
    float ry = m[4] * fxp + m[5] * fyp + m[6];
    float rz = m[8] * fxp + m[9] * fyp + m[10];
    float X = d * rx + m[3];
    float Y = d * ry + m[7];
    float Z = d * rz + m[11];

    float px = X / (Z + EPSF);
    float py = Y / (Z + EPSF);
    float gx = (px / (float)(WW - 1) - 0.5f) * 2.0f;
    float gy = (py / (float)(HH - 1) - 0.5f) * 2.0f;

    // grid_sample (border padding), exact reference formula order
    float ix = ((gx + 1.0f) * (float)WW - 1.0f) * 0.5f;
    float iy = ((gy + 1.0f) * (float)HH - 1.0f) * 0.5f;
    float ix0 = floorf(ix);
    float iy0 = floorf(iy);
    float wx = ix - ix0;
    float wy = iy - iy0;

    float ix0f = fminf(fmaxf(ix0, 0.0f), (float)(WW - 1));
    float ix1f = fminf(fmaxf(ix0 + 1.0f, 0.0f), (float)(WW - 1));
    float iy0f = fminf(fmaxf(iy0, 0.0f), (float)(HH - 1));
    float iy1f = fminf(fmaxf(iy0 + 1.0f, 0.0f), (float)(HH - 1));
    int ix0c = (int)ix0f, ix1c = (int)ix1f;
    int iy0c = (int)iy0f, iy1c = (int)iy1f;

    int i00 = iy0c * WW + ix0c;
    int i01 = iy0c * WW + ix1c;
    int i10 = iy1c * WW + ix0c;
    int i11 = iy1c * WW + ix1c;

    float w00 = (1.0f - wx) * (1.0f - wy);
    float w01 = wx * (1.0f - wy);
    float w10 = (1.0f - wx) * wy;
    float w11 = wx * wy;

    const float* imb = img + (size_t)b * 3 * HW;
    float* ob = out + (size_t)b * 3 * HW;
    #pragma unroll
    for (int c = 0; c < 3; ++c) {
        const float* pch = imb + c * HW;
        float v = pch[i00] * w00 + pch[i01] * w01 + pch[i10] * w10 + pch[i11] * w11;
        ob[c * HW + p] = v;
    }
}

extern "C" void kernel_launch(void* const* d_in, const int* in_sizes, int n_in,
                              void* d_out, int out_size, void* d_ws, size_t ws_size,
                              hipStream_t stream) {
    const float* img   = (const float*)d_in[0];
    const float* depth = (const float*)d_in[1];
    const float* T     = (const float*)d_in[2];
    const float* K     = (const float*)d_in[3];
    const float* invK  = (const float*)d_in[4];
    float* out = (float*)d_out;
    float* Mt  = (float*)d_ws;  // 16*12 floats = 768 B

    cam2cam_precompute<<<1, 64, 0, stream>>>(T, K, invK, Mt);

    const int total = BB * HH * WW;
    const int block = 256;
    const int grid = (total + block - 1) / block;
    cam2cam_warp<<<grid, block, 0, stream>>>(img, depth, Mt, out);
}

// Round 3
// 67.034 us; speedup vs baseline: 1.1575x; 1.1575x over previous
//
#include <hip/hip_runtime.h>

#define BB 16
#define HH 480
#define WW 640
#define EPSF 1e-7f

typedef float f32x2 __attribute__((ext_vector_type(2)));

// Per-batch fold: P = (K @ T)[:3,:]; M = P[:,:3] @ invK[:3,:3]; t = P[:,3]
// Mt[b*12 + i*4 + j] = M[i][j] (j<3), Mt[b*12 + i*4 + 3] = t[i]
__global__ void cam2cam_precompute(const float* __restrict__ T,
                                   const float* __restrict__ K,
                                   const float* __restrict__ invK,
                                   float* __restrict__ Mt) {
    int b = threadIdx.x;
    if (b >= BB) return;
    const float* Kb  = K    + b * 16;
    const float* Tb  = T    + b * 16;
    const float* iKb = invK + b * 16;
    float P[3][4];
    #pragma unroll
    for (int i = 0; i < 3; ++i) {
        #pragma unroll
        for (int j = 0; j < 4; ++j) {
            float s = 0.f;
            #pragma unroll
            for (int k = 0; k < 4; ++k) s += Kb[i * 4 + k] * Tb[k * 4 + j];
            P[i][j] = s;
        }
    }
    float* o = Mt + b * 12;
    #pragma unroll
    for (int i = 0; i < 3; ++i) {
        #pragma unroll
        for (int j = 0; j < 3; ++j) {
            float s = 0.f;
            #pragma unroll
            for (int k = 0; k < 3; ++k) s += P[i][k] * iKb[k * 4 + j];
            o[i * 4 + j] = s;
        }
        o[i * 4 + 3] = P[i][3];
    }
}

// 2 px/thread, 512 px/block. 307200 px per image / 512 = 600 blocks per image
// -> a block never crosses a batch boundary, and since WW=640 is even and
// pairs start at even p, a pair never crosses a row.
__global__ __launch_bounds__(256) void cam2cam_warp(
    const float* __restrict__ img,
    const float* __restrict__ depth,
    const float* __restrict__ Mt,
    float* __restrict__ out) {
    const int HW = HH * WW;

    // XCD-chunked swizzle: 8 XCDs, gridDim.x % 8 == 0 (9600 blocks).
    int nb = gridDim.x;
    int chunk = nb >> 3;                       // blocks per XCD
    int wid = (blockIdx.x & 7) * chunk + (blockIdx.x >> 3);

    int b = wid / 600;                         // uniform per block
    int pblk = (wid - b * 600) * 512;          // pixel offset within image
    int p = pblk + threadIdx.x * 2;

    const float* m = Mt + b * 12;
    float m0 = m[0], m1 = m[1], m2 = m[2], m3 = m[3];
    float m4 = m[4], m5 = m[5], m6 = m[6], m7 = m[7];
    float m8 = m[8], m9 = m[9], m10 = m[10], m11 = m[11];

    const float* imb = img + (size_t)b * 3 * HW;
    float* ob = out + (size_t)b * 3 * HW;

    f32x2 d2 = __builtin_nontemporal_load(
        (const f32x2*)(depth + (size_t)b * HW + p));

    float v[2][3];
    #pragma unroll
    for (int k = 0; k < 2; ++k) {
        int pk = p + k;
        int y = pk / WW;
        int x = pk - y * WW;
        float d = d2[k];

        float fxp = (float)x, fyp = (float)y;
        float rx = m0 * fxp + m1 * fyp + m2;
        float ry = m4 * fxp + m5 * fyp + m6;
        float rz = m8 * fxp + m9 * fyp + m10;
        float X = d * rx + m3;
        float Y = d * ry + m7;
        float Z = d * rz + m11;

        float px = X / (Z + EPSF);
        float py = Y / (Z + EPSF);
        float gx = (px / (float)(WW - 1) - 0.5f) * 2.0f;
        float gy = (py / (float)(HH - 1) - 0.5f) * 2.0f;

        float ix = ((gx + 1.0f) * (float)WW - 1.0f) * 0.5f;
        float iy = ((gy + 1.0f) * (float)HH - 1.0f) * 0.5f;
        float ix0 = floorf(ix);
        float iy0 = floorf(iy);
        float wx = ix - ix0;
        float wy = iy - iy0;

        float ix0f = fminf(fmaxf(ix0, 0.0f), (float)(WW - 1));
        float ix1f = fminf(fmaxf(ix0 + 1.0f, 0.0f), (float)(WW - 1));
        float iy0f = fminf(fmaxf(iy0, 0.0f), (float)(HH - 1));
        float iy1f = fminf(fmaxf(iy0 + 1.0f, 0.0f), (float)(HH - 1));
        int ix0c = (int)ix0f, ix1c = (int)ix1f;
        int iy0c = (int)iy0f, iy1c = (int)iy1f;

        int i00 = iy0c * WW + ix0c;
        int i01 = iy0c * WW + ix1c;
        int i10 = iy1c * WW + ix0c;
        int i11 = iy1c * WW + ix1c;

        float w00 = (1.0f - wx) * (1.0f - wy);
        float w01 = wx * (1.0f - wy);
        float w10 = (1.0f - wx) * wy;
        float w11 = wx * wy;

        #pragma unroll
        for (int c = 0; c < 3; ++c) {
            const float* pch = imb + c * HW;
            v[k][c] = pch[i00] * w00 + pch[i01] * w01 +
                      pch[i10] * w10 + pch[i11] * w11;
        }
    }

    #pragma unroll
    for (int c = 0; c < 3; ++c) {
        f32x2 o2;
        o2[0] = v[0][c];
        o2[1] = v[1][c];
        __builtin_nontemporal_store(o2, (f32x2*)(ob + c * HW + p));
    }
}

extern "C" void kernel_launch(void* const* d_in, const int* in_sizes, int n_in,
                              void* d_out, int out_size, void* d_ws, size_t ws_size,
                              hipStream_t stream) {
    const float* img   = (const float*)d_in[0];
    const float* depth = (const float*)d_in[1];
    const float* T     = (const float*)d_in[2];
    const float* K     = (const float*)d_in[3];
    const float* invK  = (const float*)d_in[4];
    float* out = (float*)d_out;
    float* Mt  = (float*)d_ws;  // 16*12 floats = 768 B

    cam2cam_precompute<<<1, 64, 0, stream>>>(T, K, invK, Mt);

    const int total = BB * HH * WW;           // 4,915,200
    const int block = 256;
    const int grid = total / (block * 2);     // 9600, divisible by 8
    cam2cam_warp<<<grid, block, 0, stream>>>(img, depth, Mt, out);
}

// Round 4
// 62.921 us; speedup vs baseline: 1.2332x; 1.0654x over previous
//
#include <hip/hip_runtime.h>

#define BB 16
#define HH 480
#define WW 640
#define HWsz (HH * WW)
#define EPSF 1e-7f

typedef float f32x2 __attribute__((ext_vector_type(2)));
typedef float f32x4 __attribute__((ext_vector_type(4)));
typedef unsigned short u16x4 __attribute__((ext_vector_type(4)));
typedef unsigned short u16x8 __attribute__((ext_vector_type(8)));

__device__ __forceinline__ unsigned short f2bf(float f) {
    unsigned u = __builtin_bit_cast(unsigned, f);
    unsigned r = (u + 0x7FFFu + ((u >> 16) & 1u)) >> 16;  // RTNE
    return (unsigned short)r;
}
__device__ __forceinline__ float bf2f(unsigned short s) {
    unsigned u = ((unsigned)s) << 16;
    return __builtin_bit_cast(float, u);
}

// Per-batch fold: P = (K @ T)[:3,:]; M = P[:,:3] @ invK[:3,:3]; t = P[:,3]
__global__ void cam2cam_precompute(const float* __restrict__ T,
                                   const float* __restrict__ K,
                                   const float* __restrict__ invK,
                                   float* __restrict__ Mt) {
    int b = threadIdx.x;
    if (b >= BB) return;
    const float* Kb  = K    + b * 16;
    const float* Tb  = T    + b * 16;
    const float* iKb = invK + b * 16;
    float P[3][4];
    #pragma unroll
    for (int i = 0; i < 3; ++i)
        #pragma unroll
        for (int j = 0; j < 4; ++j) {
            float s = 0.f;
            #pragma unroll
            for (int k = 0; k < 4; ++k) s += Kb[i * 4 + k] * Tb[k * 4 + j];
            P[i][j] = s;
        }
    float* o = Mt + b * 12;
    #pragma unroll
    for (int i = 0; i < 3; ++i) {
        #pragma unroll
        for (int j = 0; j < 3; ++j) {
            float s = 0.f;
            #pragma unroll
            for (int k = 0; k < 3; ++k) s += P[i][k] * iKb[k * 4 + j];
            o[i * 4 + j] = s;
        }
        o[i * 4 + 3] = P[i][3];
    }
}

// Pass 1: CHW f32 -> HWC bf16x4 ({r,g,b,0} per px, 8 B). Pure streaming.
__global__ __launch_bounds__(256) void cam2cam_pack(
    const float* __restrict__ img, u16x4* __restrict__ hwc) {
    int t = blockIdx.x * 256 + threadIdx.x;   // 4 px per thread
    int base = t * 4;
    int b = base / HWsz;
    int p = base - b * HWsz;
    const float* imb = img + (size_t)b * 3 * HWsz;
    f32x4 r  = *(const f32x4*)(imb + p);
    f32x4 g  = *(const f32x4*)(imb + HWsz + p);
    f32x4 bl = *(const f32x4*)(imb + 2 * HWsz + p);
    u16x8 lo, hi;
    lo[0] = f2bf(r[0]); lo[1] = f2bf(g[0]); lo[2] = f2bf(bl[0]); lo[3] = 0;
    lo[4] = f2bf(r[1]); lo[5] = f2bf(g[1]); lo[6] = f2bf(bl[1]); lo[7] = 0;
    hi[0] = f2bf(r[2]); hi[1] = f2bf(g[2]); hi[2] = f2bf(bl[2]); hi[3] = 0;
    hi[4] = f2bf(r[3]); hi[5] = f2bf(g[3]); hi[6] = f2bf(bl[3]); hi[7] = 0;
    u16x8* dst = (u16x8*)(hwc + base);
    dst[0] = lo;
    dst[1] = hi;
}

// Pass 2: warp+gather from HWC. 4 px/thread, 1024 px/block, 300 blocks/image.
__global__ __launch_bounds__(256) void cam2cam_warp(
    const u16x4* __restrict__ hwc,
    const float* __restrict__ depth,
    const float* __restrict__ Mt,
    float* __restrict__ out) {
    // XCD-chunked swizzle (gridDim.x = 4800, divisible by 8)
    int chunk = gridDim.x >> 3;
    int wid = (blockIdx.x & 7) * chunk + (blockIdx.x >> 3);
    int b = wid / 300;
    int p0 = (wid - b * 300) * 1024 + threadIdx.x * 4;

    const float* m = Mt + b * 12;
    float m0 = m[0], m1 = m[1], m2 = m[2], m3 = m[3];
    float m4 = m[4], m5 = m[5], m6 = m[6], m7 = m[7];
    float m8 = m[8], m9 = m[9], m10 = m[10], m11 = m[11];

    const u16x4* hb = hwc + (size_t)b * HWsz;
    float* ob = out + (size_t)b * 3 * HWsz;

    f32x4 d4 = __builtin_nontemporal_load(
        (const f32x4*)(depth + (size_t)b * HWsz + p0));

    float v[4][3];
    #pragma unroll
    for (int k = 0; k < 4; ++k) {
        int pk = p0 + k;
        int y = pk / WW;
        int x = pk - y * WW;
        float d = d4[k];

        float fxp = (float)x, fyp = (float)y;
        float rx = m0 * fxp + m1 * fyp + m2;
        float ry = m4 * fxp + m5 * fyp + m6;
        float rz = m8 * fxp + m9 * fyp + m10;
        float X = d * rx + m3;
        float Y = d * ry + m7;
        float Z = d * rz + m11;

        float px = X / (Z + EPSF);
        float py = Y / (Z + EPSF);
        float gx = (px / (float)(WW - 1) - 0.5f) * 2.0f;
        float gy = (py / (float)(HH - 1) - 0.5f) * 2.0f;

        float ix = ((gx + 1.0f) * (float)WW - 1.0f) * 0.5f;
        float iy = ((gy + 1.0f) * (float)HH - 1.0f) * 0.5f;
        float ix0 = floorf(ix);
        float iy0 = floorf(iy);
        float wx = ix - ix0;
        float wy = iy - iy0;

        float ix0f = fminf(fmaxf(ix0, 0.0f), (float)(WW - 1));
        float ix1f = fminf(fmaxf(ix0 + 1.0f, 0.0f), (float)(WW - 1));
        float iy0f = fminf(fmaxf(iy0, 0.0f), (float)(HH - 1));
        float iy1f = fminf(fmaxf(iy0 + 1.0f, 0.0f), (float)(HH - 1));
        int ix0c = (int)ix0f, ix1c = (int)ix1f;
        int iy0c = (int)iy0f, iy1c = (int)iy1f;

        u16x4 t00 = hb[iy0c * WW + ix0c];
        u16x4 t01 = hb[iy0c * WW + ix1c];
        u16x4 t10 = hb[iy1c * WW + ix0c];
        u16x4 t11 = hb[iy1c * WW + ix1c];

        float w00 = (1.0f - wx) * (1.0f - wy);
        float w01 = wx * (1.0f - wy);
        float w10 = (1.0f - wx) * wy;
        float w11 = wx * wy;

        #pragma unroll
        for (int c = 0; c < 3; ++c) {
            v[k][c] = bf2f(t00[c]) * w00 + bf2f(t01[c]) * w01 +
                      bf2f(t10[c]) * w10 + bf2f(t11[c]) * w11;
        }
    }

    #pragma unroll
    for (int c = 0; c < 3; ++c) {
        f32x4 o4;
        o4[0] = v[0][c]; o4[1] = v[1][c]; o4[2] = v[2][c]; o4[3] = v[3][c];
        __builtin_nontemporal_store(o4, (f32x4*)(ob + c * HWsz + p0));
    }
}

// Fallback (R3): direct CHW gather, 2 px/thread, if workspace is too small.
__global__ __launch_bounds__(256) void cam2cam_warp_direct(
    const float* __restrict__ img,
    const float* __restrict__ depth,
    const float* __restrict__ Mt,
    float* __restrict__ out) {
    int chunk = gridDim.x >> 3;
    int wid = (blockIdx.x & 7) * chunk + (blockIdx.x >> 3);
    int b = wid / 600;
    int p = (wid - b * 600) * 512 + threadIdx.x * 2;

    const float* m = Mt + b * 12;
    float m0 = m[0], m1 = m[1], m2 = m[2], m3 = m[3];
    float m4 = m[4], m5 = m[5], m6 = m[6], m7 = m[7];
    float m8 = m[8], m9 = m[9], m10 = m[10], m11 = m[11];

    const float* imb = img + (size_t)b * 3 * HWsz;
    float* ob = out + (size_t)b * 3 * HWsz;
    f32x2 d2 = __builtin_nontemporal_load(
        (const f32x2*)(depth + (size_t)b * HWsz + p));

    float v[2][3];
    #pragma unroll
    for (int k = 0; k < 2; ++k) {
        int pk = p + k;
        int y = pk / WW;
        int x = pk - y * WW;
        float d = d2[k];
        float fxp = (float)x, fyp = (float)y;
        float rx = m0 * fxp + m1 * fyp + m2;
        float ry = m4 * fxp + m5 * fyp + m6;
        float rz = m8 * fxp + m9 * fyp + m10;
        float X = d * rx + m3;
        float Y = d * ry + m7;
        float Z = d * rz + m11;
        float px = X / (Z + EPSF);
        float py = Y / (Z + EPSF);
        float gx = (px / (float)(WW - 1) - 0.5f) * 2.0f;
        float gy = (py / (float)(HH - 1) - 0.5f) * 2.0f;
        float ix = ((gx + 1.0f) * (float)WW - 1.0f) * 0.5f;
        float iy = ((gy + 1.0f) * (float)HH - 1.0f) * 0.5f;
        float ix0 = floorf(ix);
        float iy0 = floorf(iy);
        float wx = ix - ix0;
        float wy = iy - iy0;
        float ix0f = fminf(fmaxf(ix0, 0.0f), (float)(WW - 1));
        float ix1f = fminf(fmaxf(ix0 + 1.0f, 0.0f), (float)(WW - 1));
        float iy0f = fminf(fmaxf(iy0, 0.0f), (float)(HH - 1));
        float iy1f = fminf(fmaxf(iy0 + 1.0f, 0.0f), (float)(HH - 1));
        int ix0c = (int)ix0f, ix1c = (int)ix1f;
        int iy0c = (int)iy0f, iy1c = (int)iy1f;
        int i00 = iy0c * WW + ix0c;
        int i01 = iy0c * WW + ix1c;
        int i10 = iy1c * WW + ix0c;
        int i11 = iy1c * WW + ix1c;
        float w00 = (1.0f - wx) * (1.0f - wy);
        float w01 = wx * (1.0f - wy);
        float w10 = (1.0f - wx) * wy;
        float w11 = wx * wy;
        #pragma unroll
        for (int c = 0; c < 3; ++c) {
            const float* pch = imb + c * HWsz;
            v[k][c] = pch[i00] * w00 + pch[i01] * w01 +
                      pch[i10] * w10 + pch[i11] * w11;
        }
    }
    #pragma unroll
    for (int c = 0; c < 3; ++c) {
        f32x2 o2;
        o2[0] = v[0][c];
        o2[1] = v[1][c];
        __builtin_nontemporal_store(o2, (f32x2*)(ob + c * HWsz + p));
    }
}

extern "C" void kernel_launch(void* const* d_in, const int* in_sizes, int n_in,
                              void* d_out, int out_size, void* d_ws, size_t ws_size,
                              hipStream_t stream) {
    const float* img   = (const float*)d_in[0];
    const float* depth = (const float*)d_in[1];
    const float* T     = (const float*)d_in[2];
    const float* K     = (const float*)d_in[3];
    const float* invK  = (const float*)d_in[4];
    float* out = (float*)d_out;

    float* Mt = (float*)d_ws;                       // 768 B
    u16x4* hwc = (u16x4*)((char*)d_ws + 1024);      // BB*HW*8 = 39.3 MB
    size_t need = 1024 + (size_t)BB * HWsz * 8;

    cam2cam_precompute<<<1, 64, 0, stream>>>(T, K, invK, Mt);

    if (ws_size >= need) {
        const int pack_blocks = BB * HWsz / (256 * 4);   // 4800
        cam2cam_pack<<<pack_blocks, 256, 0, stream>>>(img, hwc);
        cam2cam_warp<<<pack_blocks, 256, 0, stream>>>(hwc, depth, Mt, out);
    } else {
        const int grid = BB * HWsz / (256 * 2);          // 9600
        cam2cam_warp_direct<<<grid, 256, 0, stream>>>(img, depth, Mt, out);
    }
}